// Round 1
// baseline (1104.616 us; speedup 1.0000x reference)
//
#include <hip/hip_runtime.h>
#include <math.h>

#define NUM_USERS 100000
#define NUM_ITEMS 50000
#define NN 150000          // total nodes
#define EE 1200000         // total directed edges (2 * E_DIR)
#define DD 64

// ---------------- edge MLP: edge_w = sigmoid(relu(f @ w1 + b1) @ w2 + b2) ----
__global__ void edge_mlp_kernel(const float* __restrict__ feats,
                                const float* __restrict__ w1,
                                const float* __restrict__ b1,
                                const float* __restrict__ w2,
                                const float* __restrict__ b2,
                                float* __restrict__ ew) {
    __shared__ float sw1[256];
    __shared__ float sb1[32];
    __shared__ float sw2[32];
    __shared__ float sb2;
    int t = threadIdx.x;
    sw1[t] = w1[t];                       // blockDim.x == 256
    if (t < 32) { sb1[t] = b1[t]; sw2[t] = w2[t]; }
    if (t == 0) sb2 = b2[0];
    __syncthreads();
    int e = blockIdx.x * 256 + t;
    if (e >= EE) return;
    const float4* fp = (const float4*)(feats + (size_t)e * 8);
    float4 fa = fp[0], fb = fp[1];
    float f[8] = {fa.x, fa.y, fa.z, fa.w, fb.x, fb.y, fb.z, fb.w};
    float s = sb2;
#pragma unroll
    for (int j = 0; j < 32; ++j) {
        float h = sb1[j];
#pragma unroll
        for (int i = 0; i < 8; ++i) h = fmaf(f[i], sw1[i * 32 + j], h);
        h = fmaxf(h, 0.f);
        s = fmaf(h, sw2[j], s);
    }
    ew[e] = 1.f / (1.f + expf(-s));
}

// ---------------- deg[col] += edge_w ----------------------------------------
__global__ void deg_kernel(const float* __restrict__ ew,
                           const int* __restrict__ col,
                           float* __restrict__ deg) {
    int e = blockIdx.x * 256 + threadIdx.x;
    if (e >= EE) return;
    atomicAdd(&deg[col[e]], ew[e]);
}

// ---------------- dinv = deg>0 ? 1/sqrt(deg) : 0  (in place) ----------------
__global__ void dinv_kernel(float* __restrict__ deg) {
    int i = blockIdx.x * 256 + threadIdx.x;
    if (i >= NN) return;
    float d = deg[i];
    deg[i] = (d > 0.f) ? (1.f / sqrtf(d)) : 0.f;
}

// ---------------- norm = dinv[row]*ew*dinv[col]  (in place over ew) ---------
__global__ void norm_kernel(float* __restrict__ ew,
                            const float* __restrict__ dinv,
                            const int* __restrict__ row,
                            const int* __restrict__ col) {
    int e = blockIdx.x * 256 + threadIdx.x;
    if (e >= EE) return;
    ew[e] = dinv[row[e]] * ew[e] * dinv[col[e]];
}

// ---------------- x0: per-node l2norm of features; acc = x0 -----------------
__global__ void init_x_kernel(const float* __restrict__ user_w,
                              const float* __restrict__ audio,
                              const float* __restrict__ artist_w,
                              const float* __restrict__ album_w,
                              const int* __restrict__ artist_ids,
                              const int* __restrict__ album_ids,
                              float* __restrict__ x,
                              float* __restrict__ acc) {
    unsigned t = blockIdx.x * 256u + threadIdx.x;
    unsigned node = t >> 6, lane = t & 63u;
    if (node >= NN) return;
    float v;
    if (node < NUM_USERS) {
        v = user_w[node * 64u + lane];
    } else {
        unsigned j = node - NUM_USERS;
        unsigned a = (unsigned)artist_ids[j], b = (unsigned)album_ids[j];
        v = fmaf(0.44f, artist_w[a * 64u + lane] + album_w[b * 64u + lane],
                 0.3f * audio[j * 64u + lane]);
    }
    float s = v * v;
#pragma unroll
    for (int off = 32; off > 0; off >>= 1) s += __shfl_xor(s, off, 64);
    float n = fmaxf(sqrtf(s), 1e-12f);
    float o = v / n;
    x[node * 64u + lane]   = o;
    acc[node * 64u + lane] = o;
}

// ---------------- y[col] += norm * x[row]  (one 64-lane group per edge) -----
__global__ void spmm_scatter_kernel(const float* __restrict__ x,
                                    float* __restrict__ y,
                                    const float* __restrict__ nrm,
                                    const int* __restrict__ row,
                                    const int* __restrict__ col) {
    unsigned t = blockIdx.x * 256u + threadIdx.x;
    unsigned e = t >> 6, lane = t & 63u;
    if (e >= EE) return;
    float w = nrm[e];                       // wave-uniform
    unsigned r = (unsigned)row[e], c = (unsigned)col[e];
    float v = x[r * 64u + lane];
    atomicAdd(&y[c * 64u + lane], w * v);
}

// ---------------- acc += xnew (float4) --------------------------------------
__global__ void acc_add_kernel(float* __restrict__ acc,
                               const float* __restrict__ xnew) {
    unsigned i = blockIdx.x * 256u + threadIdx.x;
    if (i >= (unsigned)NN * 16u) return;    // NN*64/4 float4 elements
    float4 a = ((float4*)acc)[i];
    float4 b = ((const float4*)xnew)[i];
    a.x += b.x; a.y += b.y; a.z += b.z; a.w += b.w;
    ((float4*)acc)[i] = a;
}

// ---------------- out = l2norm(acc/4); align_loss = 0 -----------------------
__global__ void finalize_kernel(float* __restrict__ out) {
    unsigned t = blockIdx.x * 256u + threadIdx.x;
    unsigned node = t >> 6, lane = t & 63u;
    if (node >= NN) return;
    float v = out[node * 64u + lane] * 0.25f;
    float s = v * v;
#pragma unroll
    for (int off = 32; off > 0; off >>= 1) s += __shfl_xor(s, off, 64);
    float n = fmaxf(sqrtf(s), 1e-12f);
    out[node * 64u + lane] = v / n;
    if (t == 0) out[(size_t)NN * 64u] = 0.0f;   // align_loss
}

extern "C" void kernel_launch(void* const* d_in, const int* in_sizes, int n_in,
                              void* d_out, int out_size, void* d_ws, size_t ws_size,
                              hipStream_t stream) {
    const float* user_w     = (const float*)d_in[0];
    const float* audio      = (const float*)d_in[1];
    const float* artist_w   = (const float*)d_in[2];
    const float* album_w    = (const float*)d_in[3];
    const float* w1         = (const float*)d_in[4];
    const float* b1         = (const float*)d_in[5];
    const float* w2         = (const float*)d_in[6];
    const float* b2         = (const float*)d_in[7];
    const float* feats      = (const float*)d_in[8];
    const int*   row        = (const int*)d_in[9];
    const int*   col        = row + EE;
    const int*   artist_ids = (const int*)d_in[10];
    const int*   album_ids  = (const int*)d_in[11];
    float* out = (float*)d_out;

    // workspace layout (fp32): ew[EE] | deg[NN] | xa[NN*64] | xb[NN*64]  ~82 MB
    float* ew  = (float*)d_ws;
    float* deg = ew + EE;
    float* xa  = deg + NN;
    float* xb  = xa + (size_t)NN * 64;

    hipMemsetAsync(deg, 0, NN * sizeof(float), stream);
    edge_mlp_kernel<<<(EE + 255) / 256, 256, 0, stream>>>(feats, w1, b1, w2, b2, ew);
    deg_kernel<<<(EE + 255) / 256, 256, 0, stream>>>(ew, col, deg);
    dinv_kernel<<<(NN + 255) / 256, 256, 0, stream>>>(deg);
    norm_kernel<<<(EE + 255) / 256, 256, 0, stream>>>(ew, deg, row, col);
    init_x_kernel<<<(NN * 64) / 256, 256, 0, stream>>>(user_w, audio, artist_w, album_w,
                                                       artist_ids, album_ids, xa, out);
    for (int l = 0; l < 3; ++l) {
        hipMemsetAsync(xb, 0, (size_t)NN * 64 * sizeof(float), stream);
        spmm_scatter_kernel<<<(EE * 64) / 256, 256, 0, stream>>>(xa, xb, ew, row, col);
        acc_add_kernel<<<(NN * 16 + 255) / 256, 256, 0, stream>>>(out, xb);
        float* tmp = xa; xa = xb; xb = tmp;
    }
    finalize_kernel<<<(NN * 64) / 256, 256, 0, stream>>>(out);
}

// Round 2
// 656.122 us; speedup vs baseline: 1.6836x; 1.6836x over previous
//
#include <hip/hip_runtime.h>
#include <math.h>

#define NUM_USERS 100000
#define NUM_ITEMS 50000
#define NN 150000               // total nodes
#define EE 1200000              // total directed edges (2 * E_DIR)
#define NB 586                  // ceil(NN/256) scan blocks
#define NNP (NB * 256)          // padded node count = 150016

// ---- fused edge MLP + degree histogram --------------------------------------
// ew[e] = sigmoid(relu(f @ w1 + b1) @ w2 + b2); deg[col]+=ew; counts[col]+=1
__global__ void mlp_deg_kernel(const float* __restrict__ feats,
                               const float* __restrict__ w1,
                               const float* __restrict__ b1,
                               const float* __restrict__ w2,
                               const float* __restrict__ b2,
                               const int* __restrict__ col,
                               float* __restrict__ ew,
                               float* __restrict__ deg,
                               int* __restrict__ counts) {
    __shared__ float sw1[256];
    __shared__ float sb1[32];
    __shared__ float sw2[32];
    __shared__ float sb2;
    int t = threadIdx.x;
    sw1[t] = w1[t];
    if (t < 32) { sb1[t] = b1[t]; sw2[t] = w2[t]; }
    if (t == 0) sb2 = b2[0];
    __syncthreads();
    int e = blockIdx.x * 256 + t;
    if (e >= EE) return;
    const float4* fp = (const float4*)(feats + (size_t)e * 8);
    float4 fa = fp[0], fb = fp[1];
    float f[8] = {fa.x, fa.y, fa.z, fa.w, fb.x, fb.y, fb.z, fb.w};
    float s = sb2;
#pragma unroll
    for (int j = 0; j < 32; ++j) {
        float h = sb1[j];
#pragma unroll
        for (int i = 0; i < 8; ++i) h = fmaf(f[i], sw1[i * 32 + j], h);
        h = fmaxf(h, 0.f);
        s = fmaf(h, sw2[j], s);
    }
    float w = 1.f / (1.f + expf(-s));
    ew[e] = w;
    int c = col[e];
    atomicAdd(&deg[c], w);
    atomicAdd(&counts[c], 1);
}

// ---- dinv = deg>0 ? 1/sqrt(deg) : 0  (in place) -----------------------------
__global__ void dinv_kernel(float* __restrict__ deg) {
    int i = blockIdx.x * 256 + threadIdx.x;
    if (i >= NN) return;
    float d = deg[i];
    deg[i] = (d > 0.f) ? (1.f / sqrtf(d)) : 0.f;
}

// ---- scan step 1: per-block exclusive scan of counts; block totals ----------
__global__ void scan1_kernel(const int* __restrict__ counts,
                             int* __restrict__ offs,
                             int* __restrict__ partials) {
    int i = blockIdx.x * 256 + threadIdx.x;
    int lane = threadIdx.x & 63;
    int v = (i < NN) ? counts[i] : 0;
    int s = v;
#pragma unroll
    for (int off = 1; off < 64; off <<= 1) {
        int u = __shfl_up(s, off, 64);
        if (lane >= off) s += u;
    }
    __shared__ int wsum[4];
    if (lane == 63) wsum[threadIdx.x >> 6] = s;
    __syncthreads();
    int add = 0;
    for (int w = 0; w < (threadIdx.x >> 6); ++w) add += wsum[w];
    offs[i] = s - v + add;                       // exclusive within block
    if (threadIdx.x == 255) partials[blockIdx.x] = s + add;  // block total
}

// ---- scan step 2: single-block exclusive scan of the NB partials ------------
__global__ void scan2_kernel(int* __restrict__ partials, int nb) {
    __shared__ int wsum[4];
    __shared__ int carry;
    if (threadIdx.x == 0) carry = 0;
    __syncthreads();
    int lane = threadIdx.x & 63;
    for (int base = 0; base < nb; base += 256) {
        int i = base + threadIdx.x;
        int v = (i < nb) ? partials[i] : 0;
        int s = v;
#pragma unroll
        for (int off = 1; off < 64; off <<= 1) {
            int u = __shfl_up(s, off, 64);
            if (lane >= off) s += u;
        }
        if (lane == 63) wsum[threadIdx.x >> 6] = s;
        __syncthreads();
        int add = 0;
        for (int w = 0; w < (threadIdx.x >> 6); ++w) add += wsum[w];
        int excl = s - v + add + carry;
        if (i < nb) partials[i] = excl;
        __syncthreads();
        if (threadIdx.x == 255) carry = excl + v;   // += chunk total
        __syncthreads();
    }
}

// ---- scan step 3: add block bases; duplicate into cursors -------------------
__global__ void scan3_kernel(int* __restrict__ offs,
                             const int* __restrict__ partials,
                             int* __restrict__ cursors) {
    int i = blockIdx.x * 256 + threadIdx.x;
    int v = offs[i] + partials[blockIdx.x];
    offs[i] = v;
    cursors[i] = v;
}

// ---- fill CSR: srow[k]=row, snorm[k]=dinv[row]*ew*dinv[col] -----------------
__global__ void fill_kernel(const float* __restrict__ ew,
                            const float* __restrict__ dinv,
                            const int* __restrict__ row,
                            const int* __restrict__ col,
                            int* __restrict__ cursors,
                            int* __restrict__ srow,
                            float* __restrict__ snorm) {
    int e = blockIdx.x * 256 + threadIdx.x;
    if (e >= EE) return;
    int r = row[e], c = col[e];
    int k = atomicAdd(&cursors[c], 1);
    srow[k] = r;
    snorm[k] = dinv[r] * ew[e] * dinv[c];
}

// ---- x0: per-node l2norm of features; acc(out) = x0 -------------------------
__global__ void init_x_kernel(const float* __restrict__ user_w,
                              const float* __restrict__ audio,
                              const float* __restrict__ artist_w,
                              const float* __restrict__ album_w,
                              const int* __restrict__ artist_ids,
                              const int* __restrict__ album_ids,
                              float* __restrict__ x,
                              float* __restrict__ acc) {
    unsigned t = blockIdx.x * 256u + threadIdx.x;
    unsigned node = t >> 6, lane = t & 63u;
    if (node >= NN) return;
    float v;
    if (node < NUM_USERS) {
        v = user_w[node * 64u + lane];
    } else {
        unsigned j = node - NUM_USERS;
        unsigned a = (unsigned)artist_ids[j], b = (unsigned)album_ids[j];
        v = fmaf(0.44f, artist_w[a * 64u + lane] + album_w[b * 64u + lane],
                 0.3f * audio[j * 64u + lane]);
    }
    float s = v * v;
#pragma unroll
    for (int off = 32; off > 0; off >>= 1) s += __shfl_xor(s, off, 64);
    float n = fmaxf(sqrtf(s), 1e-12f);
    float o = v / n;
    x[node * 64u + lane]   = o;
    acc[node * 64u + lane] = o;
}

// ---- CSR-gather SpMM: one 64-lane wave per destination node -----------------
// FINAL=0: y[node]=a, out[node]+=a.  FINAL=1: out[node]=l2norm((out+a)/4).
template <int FINAL>
__global__ void spmm_gather_kernel(const float* __restrict__ x,
                                   const int* __restrict__ srow,
                                   const float* __restrict__ snorm,
                                   const int* __restrict__ offs,
                                   float* __restrict__ y,
                                   float* __restrict__ out) {
    unsigned t = blockIdx.x * 256u + threadIdx.x;
    unsigned node = t >> 6, lane = t & 63u;
    if (node >= NN) return;
    int beg = offs[node], end = offs[node + 1];
    float a = 0.f;
    for (int base = beg; base < end; base += 64) {
        int m = end - base; if (m > 64) m = 64;
        int r = 0; float w = 0.f;
        if ((int)lane < m) { r = srow[base + lane]; w = snorm[base + lane]; }
        for (int j = 0; j < m; ++j) {
            int   rj = __shfl(r, j, 64);
            float wj = __shfl(w, j, 64);
            a = fmaf(wj, x[(unsigned)rj * 64u + lane], a);
        }
    }
    if (FINAL) {
        float v = (out[node * 64u + lane] + a) * 0.25f;
        float s = v * v;
#pragma unroll
        for (int off = 32; off > 0; off >>= 1) s += __shfl_xor(s, off, 64);
        float n = fmaxf(sqrtf(s), 1e-12f);
        out[node * 64u + lane] = v / n;
        if (t == 0) out[(size_t)NN * 64u] = 0.f;     // align_loss
    } else {
        y[node * 64u + lane] = a;
        out[node * 64u + lane] += a;
    }
}

extern "C" void kernel_launch(void* const* d_in, const int* in_sizes, int n_in,
                              void* d_out, int out_size, void* d_ws, size_t ws_size,
                              hipStream_t stream) {
    const float* user_w     = (const float*)d_in[0];
    const float* audio      = (const float*)d_in[1];
    const float* artist_w   = (const float*)d_in[2];
    const float* album_w    = (const float*)d_in[3];
    const float* w1         = (const float*)d_in[4];
    const float* b1         = (const float*)d_in[5];
    const float* w2         = (const float*)d_in[6];
    const float* b2         = (const float*)d_in[7];
    const float* feats      = (const float*)d_in[8];
    const int*   row        = (const int*)d_in[9];
    const int*   col        = row + EE;
    const int*   artist_ids = (const int*)d_in[10];
    const int*   album_ids  = (const int*)d_in[11];
    float* out = (float*)d_out;

    // workspace layout (4B units), ~94 MB total
    float* ew       = (float*)d_ws;          // EE
    float* deg      = ew + EE;               // NN   (becomes dinv in place)
    int*   counts   = (int*)(deg + NN);      // NNP
    int*   offs     = counts + NNP;          // NNP + 16
    int*   cursors  = offs + NNP + 16;       // NNP
    int*   partials = cursors + NNP;         // 1024
    int*   srow     = partials + 1024;       // EE
    float* snorm    = (float*)(srow + EE);   // EE
    float* xa       = snorm + EE;            // NN*64
    float* xb       = xa + (size_t)NN * 64;  // NN*64

    // zero deg + counts in one shot (they are adjacent)
    hipMemsetAsync(deg, 0, (NN + NNP) * sizeof(float), stream);

    mlp_deg_kernel<<<(EE + 255) / 256, 256, 0, stream>>>(feats, w1, b1, w2, b2,
                                                         col, ew, deg, counts);
    dinv_kernel<<<(NN + 255) / 256, 256, 0, stream>>>(deg);
    scan1_kernel<<<NB, 256, 0, stream>>>(counts, offs, partials);
    scan2_kernel<<<1, 256, 0, stream>>>(partials, NB);
    scan3_kernel<<<NB, 256, 0, stream>>>(offs, partials, cursors);
    fill_kernel<<<(EE + 255) / 256, 256, 0, stream>>>(ew, deg, row, col,
                                                      cursors, srow, snorm);
    init_x_kernel<<<(NN * 64) / 256, 256, 0, stream>>>(user_w, audio, artist_w, album_w,
                                                       artist_ids, album_ids, xa, out);
    spmm_gather_kernel<0><<<(NN * 64) / 256, 256, 0, stream>>>(xa, srow, snorm, offs, xb, out);
    spmm_gather_kernel<0><<<(NN * 64) / 256, 256, 0, stream>>>(xb, srow, snorm, offs, xa, out);
    spmm_gather_kernel<1><<<(NN * 64) / 256, 256, 0, stream>>>(xa, srow, snorm, offs, xb, out);
}

// Round 3
// 598.921 us; speedup vs baseline: 1.8443x; 1.0955x over previous
//
#include <hip/hip_runtime.h>
#include <math.h>

#define NUM_USERS 100000
#define NUM_ITEMS 50000
#define NN 150000               // total nodes
#define EE 1200000              // total directed edges (2 * E_DIR)
#define NB 586                  // ceil(NN/256) scan blocks
#define NNP (NB * 256)          // padded node count = 150016

typedef unsigned short ushort_t;
typedef unsigned int uint_t;

__device__ __forceinline__ ushort_t f2b(float f) {       // fp32 -> bf16 RNE
    uint_t b = __float_as_uint(f);
    return (ushort_t)((b + 0x7FFFu + ((b >> 16) & 1u)) >> 16);
}
__device__ __forceinline__ float b2f(ushort_t u) {       // bf16 -> fp32 exact
    return __uint_as_float(((uint_t)u) << 16);
}

// ---- fused edge MLP + count histogram ---------------------------------------
__global__ void mlp_count_kernel(const float* __restrict__ feats,
                                 const float* __restrict__ w1,
                                 const float* __restrict__ b1,
                                 const float* __restrict__ w2,
                                 const float* __restrict__ b2,
                                 const int* __restrict__ col,
                                 float* __restrict__ ew,
                                 int* __restrict__ counts) {
    __shared__ float sw1[256];
    __shared__ float sb1[32];
    __shared__ float sw2[32];
    __shared__ float sb2;
    int t = threadIdx.x;
    sw1[t] = w1[t];
    if (t < 32) { sb1[t] = b1[t]; sw2[t] = w2[t]; }
    if (t == 0) sb2 = b2[0];
    __syncthreads();
    int e = blockIdx.x * 256 + t;
    if (e >= EE) return;
    const float4* fp = (const float4*)(feats + (size_t)e * 8);
    float4 fa = fp[0], fb = fp[1];
    float f[8] = {fa.x, fa.y, fa.z, fa.w, fb.x, fb.y, fb.z, fb.w};
    float s = sb2;
#pragma unroll
    for (int j = 0; j < 32; ++j) {
        float h = sb1[j];
#pragma unroll
        for (int i = 0; i < 8; ++i) h = fmaf(f[i], sw1[i * 32 + j], h);
        h = fmaxf(h, 0.f);
        s = fmaf(h, sw2[j], s);
    }
    ew[e] = 1.f / (1.f + expf(-s));
    atomicAdd(&counts[col[e]], 1);
}

// ---- scan step 1: per-block exclusive scan of counts; block totals ----------
__global__ void scan1_kernel(const int* __restrict__ counts,
                             int* __restrict__ offs,
                             int* __restrict__ partials) {
    int i = blockIdx.x * 256 + threadIdx.x;
    int lane = threadIdx.x & 63;
    int v = counts[i];                           // [NN,NNP) pre-zeroed
    int s = v;
#pragma unroll
    for (int off = 1; off < 64; off <<= 1) {
        int u = __shfl_up(s, off, 64);
        if (lane >= off) s += u;
    }
    __shared__ int wsum[4];
    if (lane == 63) wsum[threadIdx.x >> 6] = s;
    __syncthreads();
    int add = 0;
    for (int w = 0; w < (threadIdx.x >> 6); ++w) add += wsum[w];
    offs[i] = s - v + add;
    if (threadIdx.x == 255) partials[blockIdx.x] = s + add;
}

// ---- scan step 2: single-block exclusive scan of the NB partials ------------
__global__ void scan2_kernel(int* __restrict__ partials, int nb) {
    __shared__ int wsum[4];
    __shared__ int carry;
    if (threadIdx.x == 0) carry = 0;
    __syncthreads();
    int lane = threadIdx.x & 63;
    for (int base = 0; base < nb; base += 256) {
        int i = base + threadIdx.x;
        int v = (i < nb) ? partials[i] : 0;
        int s = v;
#pragma unroll
        for (int off = 1; off < 64; off <<= 1) {
            int u = __shfl_up(s, off, 64);
            if (lane >= off) s += u;
        }
        if (lane == 63) wsum[threadIdx.x >> 6] = s;
        __syncthreads();
        int add = 0;
        for (int w = 0; w < (threadIdx.x >> 6); ++w) add += wsum[w];
        int excl = s - v + add + carry;
        if (i < nb) partials[i] = excl;
        __syncthreads();
        if (threadIdx.x == 255) carry = excl + v;
        __syncthreads();
    }
}

// ---- scan step 3: add block bases; duplicate into cursors -------------------
__global__ void scan3_kernel(int* __restrict__ offs,
                             const int* __restrict__ partials,
                             int* __restrict__ cursors) {
    int i = blockIdx.x * 256 + threadIdx.x;
    int v = offs[i] + partials[blockIdx.x];
    offs[i] = v;
    cursors[i] = v;
}

// ---- fill CSR: packed[k] = {row, ew} (one 8B store per edge) ----------------
__global__ void fill_kernel(const float* __restrict__ ew,
                            const int* __restrict__ row,
                            const int* __restrict__ col,
                            int* __restrict__ cursors,
                            int2* __restrict__ packed) {
    int e = blockIdx.x * 256 + threadIdx.x;
    if (e >= EE) return;
    int k = atomicAdd(&cursors[col[e]], 1);
    packed[k] = make_int2(row[e], __float_as_int(ew[e]));
}

// ---- deg/dinv per node from own CSR segment (atomic-free) -------------------
__global__ void dinv_kernel(const int2* __restrict__ packed,
                            const int* __restrict__ offs,
                            float* __restrict__ dinv) {
    int i = blockIdx.x * 256 + threadIdx.x;
    if (i >= NN) return;
    int beg = offs[i], end = offs[i + 1];
    float d = 0.f;
    for (int k = beg; k < end; ++k) d += __int_as_float(packed[k].y);
    dinv[i] = (d > 0.f) ? (1.f / sqrtf(d)) : 0.f;
}

// ---- scale: packed[k].w *= dinv[row]*dinv[col]  (in place) ------------------
__global__ void scale_kernel(int2* __restrict__ packed,
                             const int* __restrict__ offs,
                             const float* __restrict__ dinv) {
    int i = blockIdx.x * 256 + threadIdx.x;
    if (i >= NN) return;
    int beg = offs[i], end = offs[i + 1];
    float dc = dinv[i];
    for (int k = beg; k < end; ++k) {
        int2 p = packed[k];
        float w = __int_as_float(p.y) * dinv[p.x] * dc;
        ((float*)packed)[2 * k + 1] = w;
    }
}

// ---- x0: per-node l2norm of features, stored bf16 ---------------------------
__global__ void init_x_kernel(const float* __restrict__ user_w,
                              const float* __restrict__ audio,
                              const float* __restrict__ artist_w,
                              const float* __restrict__ album_w,
                              const int* __restrict__ artist_ids,
                              const int* __restrict__ album_ids,
                              ushort_t* __restrict__ x0) {
    unsigned t = blockIdx.x * 256u + threadIdx.x;
    unsigned node = t >> 6, lane = t & 63u;
    if (node >= NN) return;
    float v;
    if (node < NUM_USERS) {
        v = user_w[node * 64u + lane];
    } else {
        unsigned j = node - NUM_USERS;
        unsigned a = (unsigned)artist_ids[j], b = (unsigned)album_ids[j];
        v = fmaf(0.44f, artist_w[a * 64u + lane] + album_w[b * 64u + lane],
                 0.3f * audio[j * 64u + lane]);
    }
    float s = v * v;
#pragma unroll
    for (int off = 32; off > 0; off >>= 1) s += __shfl_xor(s, off, 64);
    float n = fmaxf(sqrtf(s), 1e-12f);
    x0[node * 64u + lane] = f2b(v / n);
}

// ---- CSR-gather SpMM: one 64-lane wave per destination node, bf16 x ---------
__global__ void spmm_gather_kernel(const ushort_t* __restrict__ x,
                                   const int2* __restrict__ packed,
                                   const int* __restrict__ offs,
                                   ushort_t* __restrict__ y) {
    unsigned t = blockIdx.x * 256u + threadIdx.x;
    unsigned node = t >> 6, lane = t & 63u;
    if (node >= NN) return;
    int beg = offs[node], end = offs[node + 1];
    float a = 0.f;
    for (int base = beg; base < end; base += 64) {
        int m = end - base; if (m > 64) m = 64;
        int r = 0; float w = 0.f;
        if ((int)lane < m) {
            int2 p = packed[base + lane];
            r = p.x; w = __int_as_float(p.y);
        }
        for (int j = 0; j < m; ++j) {
            int   rj = __shfl(r, j, 64);
            float wj = __shfl(w, j, 64);
            a = fmaf(wj, b2f(x[(unsigned)rj * 64u + lane]), a);
        }
    }
    y[node * 64u + lane] = f2b(a);
}

// ---- out = l2norm((x0+x1+x2+x3)/4); align_loss = 0 --------------------------
__global__ void finalize_kernel(const ushort_t* __restrict__ x0,
                                const ushort_t* __restrict__ x1,
                                const ushort_t* __restrict__ x2,
                                const ushort_t* __restrict__ x3,
                                float* __restrict__ out) {
    unsigned t = blockIdx.x * 256u + threadIdx.x;
    unsigned node = t >> 6, lane = t & 63u;
    if (node >= NN) return;
    unsigned i = node * 64u + lane;
    float v = (b2f(x0[i]) + b2f(x1[i]) + b2f(x2[i]) + b2f(x3[i])) * 0.25f;
    float s = v * v;
#pragma unroll
    for (int off = 32; off > 0; off >>= 1) s += __shfl_xor(s, off, 64);
    float n = fmaxf(sqrtf(s), 1e-12f);
    out[i] = v / n;
    if (t == 0) out[(size_t)NN * 64u] = 0.f;     // align_loss
}

extern "C" void kernel_launch(void* const* d_in, const int* in_sizes, int n_in,
                              void* d_out, int out_size, void* d_ws, size_t ws_size,
                              hipStream_t stream) {
    const float* user_w     = (const float*)d_in[0];
    const float* audio      = (const float*)d_in[1];
    const float* artist_w   = (const float*)d_in[2];
    const float* album_w    = (const float*)d_in[3];
    const float* w1         = (const float*)d_in[4];
    const float* b1         = (const float*)d_in[5];
    const float* w2         = (const float*)d_in[6];
    const float* b2         = (const float*)d_in[7];
    const float* feats      = (const float*)d_in[8];
    const int*   row        = (const int*)d_in[9];
    const int*   col        = row + EE;
    const int*   artist_ids = (const int*)d_in[10];
    const int*   album_ids  = (const int*)d_in[11];
    float* out = (float*)d_out;

    // workspace layout (4-byte units up to packed, then bf16 buffers) ~93.6 MB
    float* ew       = (float*)d_ws;               // EE
    float* dinv     = ew + EE;                    // NN
    int*   counts   = (int*)(dinv + NN);          // NNP
    int*   offs     = counts + NNP;               // NNP + 16
    int*   cursors  = offs + NNP + 16;            // NNP
    int*   partials = cursors + NNP;              // 1024
    int2*  packed   = (int2*)(partials + 1024);   // EE (8B each)
    ushort_t* x0    = (ushort_t*)(packed + EE);   // NN*64 bf16
    ushort_t* x1    = x0 + (size_t)NN * 64;
    ushort_t* x2    = x1 + (size_t)NN * 64;
    ushort_t* x3    = x2 + (size_t)NN * 64;

    hipMemsetAsync(counts, 0, NNP * sizeof(int), stream);

    mlp_count_kernel<<<(EE + 255) / 256, 256, 0, stream>>>(feats, w1, b1, w2, b2,
                                                           col, ew, counts);
    scan1_kernel<<<NB, 256, 0, stream>>>(counts, offs, partials);
    scan2_kernel<<<1, 256, 0, stream>>>(partials, NB);
    scan3_kernel<<<NB, 256, 0, stream>>>(offs, partials, cursors);
    fill_kernel<<<(EE + 255) / 256, 256, 0, stream>>>(ew, row, col, cursors, packed);
    dinv_kernel<<<(NN + 255) / 256, 256, 0, stream>>>(packed, offs, dinv);
    scale_kernel<<<(NN + 255) / 256, 256, 0, stream>>>(packed, offs, dinv);
    init_x_kernel<<<(NN * 64) / 256, 256, 0, stream>>>(user_w, audio, artist_w, album_w,
                                                       artist_ids, album_ids, x0);
    spmm_gather_kernel<<<(NN * 64) / 256, 256, 0, stream>>>(x0, packed, offs, x1);
    spmm_gather_kernel<<<(NN * 64) / 256, 256, 0, stream>>>(x1, packed, offs, x2);
    spmm_gather_kernel<<<(NN * 64) / 256, 256, 0, stream>>>(x2, packed, offs, x3);
    finalize_kernel<<<(NN * 64) / 256, 256, 0, stream>>>(x0, x1, x2, x3, out);
}